// Round 3
// baseline (350.144 us; speedup 1.0000x reference)
//
#include <hip/hip_runtime.h>

#define NN 100000
#define EE 1600000
#define FO 32

// ---------------- threefry2x32 with key (0,1) = jax.random.key(1) -------
__device__ __forceinline__ unsigned rotl32(unsigned x, unsigned r) {
    return (x << r) | (x >> (32u - r));
}

__device__ __forceinline__ void threefry2x32_01(unsigned x0, unsigned x1,
                                                unsigned& y0, unsigned& y1) {
    const unsigned ks0 = 0u, ks1 = 1u, ks2 = 0x1BD11BDBu; // 0^1^0x1BD11BDA
    x0 += ks0; x1 += ks1;
#define TF_R(r) { x0 += x1; x1 = rotl32(x1, (r)); x1 ^= x0; }
    TF_R(13) TF_R(15) TF_R(26) TF_R(6)   x0 += ks1; x1 += ks2 + 1u;
    TF_R(17) TF_R(29) TF_R(16) TF_R(24)  x0 += ks2; x1 += ks0 + 2u;
    TF_R(13) TF_R(15) TF_R(26) TF_R(6)   x0 += ks0; x1 += ks1 + 3u;
    TF_R(17) TF_R(29) TF_R(16) TF_R(24)  x0 += ks1; x1 += ks2 + 4u;
    TF_R(13) TF_R(15) TF_R(26) TF_R(6)   x0 += ks2; x1 += ks0 + 5u;
#undef TF_R
    y0 = x0; y1 = x1;
}

__device__ __forceinline__ unsigned short f2bf(float f) {   // RNE
    unsigned u = __float_as_uint(f);
    unsigned r = (u + 0x7fffu + ((u >> 16) & 1u)) >> 16;
    return (unsigned short)r;
}
__device__ __forceinline__ float bf2f(unsigned short b) {
    return __uint_as_float(((unsigned)b) << 16);
}

// ---------------- K0: detect edge_index storage width -------------------
__global__ __launch_bounds__(256) void k_detect(const unsigned* __restrict__ ei,
                                                unsigned* __restrict__ flag) {
    __shared__ unsigned red[256];
    unsigned v = 0;
    for (int i = threadIdx.x; i < 4096; i += 256) v |= ei[2 * i + 1];
    red[threadIdx.x] = v;
    __syncthreads();
    for (int s = 128; s; s >>= 1) {
        if (threadIdx.x < s) red[threadIdx.x] |= red[threadIdx.x + s];
        __syncthreads();
    }
    if (threadIdx.x == 0) *flag = (red[0] == 0u) ? 1u : 0u;  // 1 => int64
}

__device__ __forceinline__ int load_idx(const int* __restrict__ ei,
                                        int logical, unsigned wide) {
    return ei[wide ? (logical << 1) : logical];
}

// ---------------- K1: h(bf16) = x @ W, fused a_src/a_dst ----------------
__global__ __launch_bounds__(256) void k_gemm(
    const float* __restrict__ x, const float* __restrict__ W,
    const float* __restrict__ att_s, const float* __restrict__ att_d,
    unsigned short* __restrict__ h16,
    float* __restrict__ a_s, float* __restrict__ a_d)
{
    __shared__ float Ws[256 * 32];     // 32 KB
    __shared__ float xs[32 * 132];     // 16.9 KB
    const int tid = threadIdx.x;

    #pragma unroll
    for (int i = 0; i < 8; ++i) {      // stage W once (coalesced float4)
        int idx = i * 1024 + tid * 4;
        *reinterpret_cast<float4*>(Ws + idx) =
            *reinterpret_cast<const float4*>(W + idx);
    }

    const int j4 = tid & 7;            // colgroup
    const int rl = tid >> 3;           // local row 0..31
    const int c0 = j4 * 4;
    const float4 avs = *reinterpret_cast<const float4*>(att_s + c0);
    const float4 avd = *reinterpret_cast<const float4*>(att_d + c0);

    for (int tile = blockIdx.x; tile < (NN / 32); tile += gridDim.x) {
        const int row0 = tile * 32;
        float4 acc = make_float4(0.f, 0.f, 0.f, 0.f);

        for (int kc = 0; kc < 256; kc += 128) {
            __syncthreads();
            #pragma unroll
            for (int i = 0; i < 4; ++i) {          // stage 32x128 chunk
                int l = i * 1024 + tid * 4;
                int r = l >> 7, c = l & 127;
                *reinterpret_cast<float4*>(xs + r * 132 + c) =
                    *reinterpret_cast<const float4*>(
                        x + (size_t)(row0 + r) * 256 + kc + c);
            }
            __syncthreads();
            const float* xr = xs + rl * 132;
            #pragma unroll 4
            for (int k0 = 0; k0 < 128; k0 += 4) {
                float4 xv = *reinterpret_cast<const float4*>(xr + k0);
                #pragma unroll
                for (int q = 0; q < 4; ++q) {
                    float xq = (q == 0) ? xv.x : (q == 1) ? xv.y
                             : (q == 2) ? xv.z : xv.w;
                    float4 wv = *reinterpret_cast<const float4*>(
                        Ws + (kc + k0 + q) * 32 + c0);
                    acc.x = fmaf(xq, wv.x, acc.x);
                    acc.y = fmaf(xq, wv.y, acc.y);
                    acc.z = fmaf(xq, wv.z, acc.z);
                    acc.w = fmaf(xq, wv.w, acc.w);
                }
            }
        }
        const int row = row0 + rl;
        ushort4 hb;
        hb.x = f2bf(acc.x); hb.y = f2bf(acc.y);
        hb.z = f2bf(acc.z); hb.w = f2bf(acc.w);
        *reinterpret_cast<ushort4*>(h16 + (size_t)row * 32 + c0) = hb;
        float v1 = acc.x * avs.x + acc.y * avs.y + acc.z * avs.z + acc.w * avs.w;
        float v2 = acc.x * avd.x + acc.y * avd.y + acc.z * avd.z + acc.w * avd.w;
        #pragma unroll
        for (int off = 4; off; off >>= 1) {
            v1 += __shfl_xor(v1, off, 8);
            v2 += __shfl_xor(v2, off, 8);
        }
        if (j4 == 0) { a_s[row] = v1; a_d[row] = v2; }
    }
}

// ---------------- CSR build: histogram, scan, scatter -------------------
__global__ __launch_bounds__(256) void k_hist(
    const int* __restrict__ ei, const unsigned* __restrict__ flag,
    int* __restrict__ deg)
{
    int e = blockIdx.x * 256 + threadIdx.x;
    if (e >= EE) return;
    const unsigned wide = *flag;
    atomicAdd(&deg[load_idx(ei, EE + e, wide)], 1);
}

__global__ __launch_bounds__(1024) void k_scanA(
    const int* __restrict__ deg, int* __restrict__ inc, int* __restrict__ btot)
{
    __shared__ int s[1024];
    int g = blockIdx.x * 1024 + threadIdx.x;
    int v = (g < NN) ? deg[g] : 0;
    s[threadIdx.x] = v;
    __syncthreads();
    for (int off = 1; off < 1024; off <<= 1) {
        int add = (threadIdx.x >= off) ? s[threadIdx.x - off] : 0;
        __syncthreads();
        s[threadIdx.x] += add;
        __syncthreads();
    }
    if (g < NN) inc[g] = s[threadIdx.x];
    if (threadIdx.x == 1023) btot[blockIdx.x] = s[1023];
}

__global__ __launch_bounds__(128) void k_scanB(int* __restrict__ btot)
{
    __shared__ int s[128];
    int v = (threadIdx.x < 98) ? btot[threadIdx.x] : 0;
    s[threadIdx.x] = v;
    __syncthreads();
    for (int off = 1; off < 128; off <<= 1) {
        int add = (threadIdx.x >= off) ? s[threadIdx.x - off] : 0;
        __syncthreads();
        s[threadIdx.x] += add;
        __syncthreads();
    }
    if (threadIdx.x < 98) btot[threadIdx.x] = s[threadIdx.x] - v;  // exclusive
}

__global__ __launch_bounds__(1024) void k_scanC(
    const int* __restrict__ deg, int* __restrict__ inc /*-> offs*/,
    const int* __restrict__ btot, int* __restrict__ cursor)
{
    int g = blockIdx.x * 1024 + threadIdx.x;
    if (g >= NN) return;
    int o = inc[g] - deg[g] + btot[blockIdx.x];
    inc[g] = o;
    cursor[g] = o;
}

__global__ __launch_bounds__(256) void k_scatter(
    const int* __restrict__ ei, const unsigned* __restrict__ flag,
    int* __restrict__ cursor, int* __restrict__ csr)
{
    int e = blockIdx.x * 256 + threadIdx.x;
    if (e >= EE) return;
    const unsigned wide = *flag;
    int s = load_idx(ei, e, wide);
    int d = load_idx(ei, EE + e, wide);
    int p = atomicAdd(&cursor[d], 1);
    csr[p] = s;
}

// ---------------- K3: fused gather-aggregate + softmax + epilogue -------
// one 64-lane wave per dst node; 2 edges in flight (32 lanes x 1 col each)
__global__ __launch_bounds__(256) void k_aggr(
    const unsigned short* __restrict__ h16,
    const float* __restrict__ a_s, const float* __restrict__ a_d,
    const int* __restrict__ offs, const int* __restrict__ csr,
    const float* __restrict__ bias, float* __restrict__ out)
{
    const int wid  = threadIdx.x >> 6;
    const int lane = threadIdx.x & 63;
    const int half = lane >> 5;
    const int j    = lane & 31;
    const int d    = blockIdx.x * 4 + wid;          // grid exactly covers NN
    const float add = a_d[d];
    const int start = offs[d];
    const int end   = (d == NN - 1) ? EE : offs[d + 1];

    float acc = 0.f, den = 0.f;
    for (int i = start + half; i < end; i += 2) {
        int s = csr[i];
        float al = a_s[s] + add;
        al = (al >= 0.f) ? al : 0.2f * al;
        float w = expf(al);
        acc = fmaf(w, bf2f(h16[(size_t)s * 32 + j]), acc);
        den += w;
    }
    acc += __shfl_xor(acc, 32);
    den += __shfl_xor(den, 32);
    // self-loop
    {
        float al = a_s[d] + add;
        al = (al >= 0.f) ? al : 0.2f * al;
        float w = expf(al);
        acc = fmaf(w, bf2f(h16[(size_t)d * 32 + j]), acc);
        den += w;
    }
    float v = fmaxf(acc / den + bias[j], 0.f);
    int t = d * 32 + j;
    unsigned y0, y1;
    threefry2x32_01(0u, (unsigned)t, y0, y1);
    v = ((y0 ^ y1) >> 31) ? 0.f : v * 2.f;
    if (half == 0) out[t] = v;
}

extern "C" void kernel_launch(void* const* d_in, const int* in_sizes, int n_in,
                              void* d_out, int out_size, void* d_ws, size_t ws_size,
                              hipStream_t stream) {
    const float* x     = (const float*)d_in[0];
    const float* W     = (const float*)d_in[1];
    const float* att_s = (const float*)d_in[2];
    const float* att_d = (const float*)d_in[3];
    const float* bias  = (const float*)d_in[4];
    const int*   ei    = (const int*)d_in[5];
    float* out = (float*)d_out;

    // ws layout (4B words):
    // h16[NN*32 bf16 = NN*16 words] | a_s[NN] | a_d[NN] | deg[NN] | offs[NN]
    // | cursor[NN] | csr[EE] | btot[128] | flag[1]
    unsigned short* h16 = (unsigned short*)d_ws;
    float* a_s   = (float*)(h16 + (size_t)NN * FO);
    float* a_d   = a_s + NN;
    int*   deg   = (int*)(a_d + NN);
    int*   offs  = deg + NN;
    int*   cursor= offs + NN;
    int*   csr   = cursor + NN;
    int*   btot  = csr + EE;
    unsigned* flag = (unsigned*)(btot + 128);

    hipMemsetAsync(deg, 0, (size_t)NN * sizeof(int), stream);

    k_detect<<<1, 256, 0, stream>>>((const unsigned*)ei, flag);
    k_gemm<<<1024, 256, 0, stream>>>(x, W, att_s, att_d, h16, a_s, a_d);
    k_hist<<<(EE + 255) / 256, 256, 0, stream>>>(ei, flag, deg);
    k_scanA<<<98, 1024, 0, stream>>>(deg, offs, btot);
    k_scanB<<<1, 128, 0, stream>>>(btot);
    k_scanC<<<98, 1024, 0, stream>>>(deg, offs, btot, cursor);
    k_scatter<<<(EE + 255) / 256, 256, 0, stream>>>(ei, flag, cursor, csr);
    k_aggr<<<NN / 4, 256, 0, stream>>>(h16, a_s, a_d, offs, csr, bias, out);
}